// Round 3
// baseline (294.872 us; speedup 1.0000x reference)
//
#include <hip/hip_runtime.h>

// TotalVariationLoss: mean over (B,N,K) of squared distances to the K=8
// nearest neighbors (self excluded) of B*N 3D points. Only the SUM of each
// point's 8 smallest non-self d2 is needed.
//
// Design (round 3): wave = 64 queries (one per lane) x 1 candidate chunk.
// Candidate address is wave-uniform -> s_load/scalar-cache broadcast, zero
// VALU cost. Prepass packs (x,y,z,csq) float4 into d_ws. Self-exclusion is
// hoisted to a 64-wide middle segment (uniform bounds). 8 waves/block merge
// their top-8 lists in LDS once at the end.

constexpr int B_    = 4;
constexpr int N_    = 8192;
constexpr int KNN   = 8;
constexpr int WAVES = 8;              // chunks per query group = waves/block
constexpr int BLOCK = WAVES * 64;     // 512 threads
constexpr int CHUNK = N_ / WAVES;     // 1024 candidates per wave

__global__ __launch_bounds__(256)
void prepack_kernel(const float* __restrict__ pts, float4* __restrict__ p4) {
    const int i = blockIdx.x * 256 + threadIdx.x;
    if (i < B_ * N_) {
        const float x = pts[i * 3 + 0], y = pts[i * 3 + 1], z = pts[i * 3 + 2];
        p4[i] = make_float4(x, y, z, fmaf(x, x, fmaf(y, y, z * z)));
    }
}

__global__ __launch_bounds__(BLOCK, 4)
void knn_tv_kernel(const float4* __restrict__ p4, float* __restrict__ out) {
    __shared__ float lists[BLOCK][KNN + 1];   // +1 pad -> conflict-free merge

    const int tid  = threadIdx.x;
    const int lane = tid & 63;
    const int w    = tid >> 6;                // wave id == chunk id
    const int g    = blockIdx.x;              // query group (64 queries)
    const int b    = g >> 7;                  // 128 groups per batch
    const int qbase = (g & 127) << 6;

    const float4* __restrict__ cnd = p4 + b * N_ + w * CHUNK;
    const float4 q  = p4[b * N_ + qbase + lane];      // coalesced 16B/lane
    const float qsq = q.w;
    const float m2x = -2.0f * q.x, m2y = -2.0f * q.y, m2z = -2.0f * q.z;

    float h[KNN];                             // ascending top-8, h[7]=worst
#pragma unroll
    for (int k = 0; k < KNN; ++k) h[k] = 1e30f;

    // Middle segment [s0,s1) contains this wave's queries as candidates.
    const int qsel = qbase - w * CHUNK;
    int s0 = 0, s1 = 0;
    if (qsel >= 0 && qsel < CHUNK) { s0 = qsel; s1 = qsel + 64; }

    auto scan = [&](int lo, int hi, bool selfseg) {
#pragma unroll 8
        for (int i = lo; i < hi; ++i) {
            const float4 s = cnd[i];          // wave-uniform -> scalar load
            float d2 = fmaf(m2x, s.x, fmaf(m2y, s.y, fmaf(m2z, s.z, qsq + s.w)));
            if (selfseg) d2 = (lane == i - qsel) ? 1e30f : d2;
            if (__any(d2 < h[KNN - 1])) {
                float d = d2;                 // bubble through ascending list
#pragma unroll
                for (int k = 0; k < KNN; ++k) {
                    const float lo2 = fminf(h[k], d);
                    d    = fmaxf(h[k], d);
                    h[k] = lo2;
                }
            }
        }
    };
    scan(0, s0, false);
    scan(s0, s1, true);                       // self handled here only
    scan(s1, CHUNK, false);

#pragma unroll
    for (int k = 0; k < KNN; ++k) lists[tid][k] = h[k];
    __syncthreads();

    if (tid < 64) {                           // wave 0 merges 8 lists/query
        float m[KNN];
#pragma unroll
        for (int k = 0; k < KNN; ++k) m[k] = 1e30f;
        for (int ww = 0; ww < WAVES; ++ww) {
#pragma unroll
            for (int k = 0; k < KNN; ++k) {
                float d = lists[ww * 64 + tid][k];
#pragma unroll
                for (int kk = 0; kk < KNN; ++kk) {
                    const float lo2 = fminf(m[kk], d);
                    d     = fmaxf(m[kk], d);
                    m[kk] = lo2;
                }
            }
        }
        float qsum = 0.0f;
#pragma unroll
        for (int k = 0; k < KNN; ++k) qsum += m[k];
#pragma unroll
        for (int off = 32; off >= 1; off >>= 1) qsum += __shfl_xor(qsum, off, 64);
        if (tid == 0)
            atomicAdd(out, qsum * (1.0f / ((float)B_ * N_ * KNN)));
    }
}

extern "C" void kernel_launch(void* const* d_in, const int* in_sizes, int n_in,
                              void* d_out, int out_size, void* d_ws, size_t ws_size,
                              hipStream_t stream) {
    const float* pts = (const float*)d_in[0];
    float* out = (float*)d_out;
    float4* p4 = (float4*)d_ws;               // B*N*16 = 512 KiB scratch

    hipMemsetAsync(out, 0, (size_t)out_size * sizeof(float), stream);
    prepack_kernel<<<(B_ * N_ + 255) / 256, 256, 0, stream>>>(pts, p4);
    knn_tv_kernel<<<B_ * (N_ / 64), BLOCK, 0, stream>>>(p4, out);
}

// Round 5
// 137.204 us; speedup vs baseline: 2.1491x; 2.1491x over previous
//
#include <hip/hip_runtime.h>

// TotalVariationLoss: mean over (B,N,K) of squared distances to the K=8
// nearest neighbors (self excluded) of B*N 3D points. Only the SUM of each
// point's 8 smallest non-self d2 is needed.
//
// Round 4 (resubmit, unmeasured): branchless selection. Per group of 8
// candidates: Batcher sort-8 (19 CE), bitonic top-8 merge with running list
// (8 min), bitonic cleanup (12 CE). No __any / no serial bubble chain
// (round-3 post-mortem: 85% wave-taken rate made the serial insert the
// bottleneck).

constexpr int B_    = 4;
constexpr int N_    = 8192;
constexpr int KNN   = 8;
constexpr int WAVES = 8;              // chunks per query group
constexpr int BLOCK = WAVES * 64;     // 512 threads
constexpr int CHUNK = N_ / WAVES;     // 1024 candidates per wave
constexpr int NG    = CHUNK / 8;      // 128 groups of 8

#define CE(a, b) { const float _lo = fminf(a, b); b = fmaxf(a, b); a = _lo; }

__global__ __launch_bounds__(256)
void prepack_kernel(const float* __restrict__ pts, float4* __restrict__ p4) {
    const int i = blockIdx.x * 256 + threadIdx.x;
    if (i < B_ * N_) {
        const float x = pts[i * 3 + 0], y = pts[i * 3 + 1], z = pts[i * 3 + 2];
        p4[i] = make_float4(x, y, z, fmaf(x, x, fmaf(y, y, z * z)));
    }
}

__global__ __launch_bounds__(BLOCK, 4)
void knn_tv_kernel(const float4* __restrict__ p4, float* __restrict__ out) {
    __shared__ float lists[(WAVES - 1) * 64][KNN + 1];   // +1 pad: 2-way max

    const int tid   = threadIdx.x;
    const int lane  = tid & 63;
    const int w     = tid >> 6;               // wave id == chunk id
    const int g     = blockIdx.x;
    const int b     = g >> 7;                 // 128 query-groups per batch
    const int qbase = (g & 127) << 6;

    // force wave-uniform candidate base -> s_load scalar broadcast
    const int chunk_off = __builtin_amdgcn_readfirstlane(b * N_ + w * CHUNK);
    const float4* __restrict__ cnd = p4 + chunk_off;

    const float4 q  = p4[b * N_ + qbase + lane];         // coalesced 16B/lane
    const float qsq = q.w;
    const float m2x = -2.0f * q.x, m2y = -2.0f * q.y, m2z = -2.0f * q.z;

    float h[KNN];                              // ascending, h[7] = worst
#pragma unroll
    for (int k = 0; k < KNN; ++k) h[k] = 1e30f;

    // groups [gs0, gs1) contain this wave's own queries as candidates
    // (qbase and w*CHUNK are multiples of 64, so qsel is 8-aligned and the
    //  8 groups cover the 64 self candidates exactly)
    const int qsel = qbase - w * CHUNK;
    const bool own = (qsel >= 0) && (qsel < CHUNK);
    const int gs0  = own ? (qsel >> 3) : NG;
    const int gs1  = own ? gs0 + 8 : NG;

    auto do_group = [&](int gg, bool fix) {
        const float4* gp = cnd + gg * 8;
        float d[8];
#pragma unroll
        for (int j = 0; j < 8; ++j) {
            const float4 s = gp[j];            // uniform -> scalar load
            float dd = fmaf(m2x, s.x, fmaf(m2y, s.y, fmaf(m2z, s.z, qsq + s.w)));
            if (fix) dd = (lane == gg * 8 + j - qsel) ? 1e30f : dd;  // self
            d[j] = dd;
        }
        // Batcher odd-even sort-8, ascending (19 CE, depth 6)
        CE(d[0], d[1]) CE(d[2], d[3]) CE(d[4], d[5]) CE(d[6], d[7])
        CE(d[0], d[2]) CE(d[1], d[3]) CE(d[4], d[6]) CE(d[5], d[7])
        CE(d[1], d[2]) CE(d[5], d[6])
        CE(d[0], d[4]) CE(d[1], d[5]) CE(d[2], d[6]) CE(d[3], d[7])
        CE(d[2], d[4]) CE(d[3], d[5])
        CE(d[1], d[2]) CE(d[3], d[4]) CE(d[5], d[6])
        // top-8 of h ∪ d (h asc, d asc): elementwise min vs reversed d -> bitonic
        float m0 = fminf(h[0], d[7]), m1 = fminf(h[1], d[6]);
        float m2 = fminf(h[2], d[5]), m3 = fminf(h[3], d[4]);
        float m4 = fminf(h[4], d[3]), m5 = fminf(h[5], d[2]);
        float m6 = fminf(h[6], d[1]), m7 = fminf(h[7], d[0]);
        // bitonic cleanup -> ascending (12 CE)
        CE(m0, m4) CE(m1, m5) CE(m2, m6) CE(m3, m7)
        CE(m0, m2) CE(m1, m3) CE(m4, m6) CE(m5, m7)
        CE(m0, m1) CE(m2, m3) CE(m4, m5) CE(m6, m7)
        h[0] = m0; h[1] = m1; h[2] = m2; h[3] = m3;
        h[4] = m4; h[5] = m5; h[6] = m6; h[7] = m7;
    };

#pragma unroll 2
    for (int gg = 0; gg < gs0; ++gg) do_group(gg, false);
    for (int gg = gs0; gg < gs1; ++gg) do_group(gg, true);
#pragma unroll 2
    for (int gg = gs1; gg < NG; ++gg) do_group(gg, false);

    // merge the 8 per-wave sorted lists (per query = per lane)
    if (w > 0) {
#pragma unroll
        for (int k = 0; k < KNN; ++k) lists[(w - 1) * 64 + lane][k] = h[k];
    }
    __syncthreads();
    if (w == 0) {
        for (int ww = 0; ww < WAVES - 1; ++ww) {
            float e[KNN];
#pragma unroll
            for (int k = 0; k < KNN; ++k) e[k] = lists[ww * 64 + lane][k];
            float m0 = fminf(h[0], e[7]), m1 = fminf(h[1], e[6]);
            float m2 = fminf(h[2], e[5]), m3 = fminf(h[3], e[4]);
            float m4 = fminf(h[4], e[3]), m5 = fminf(h[5], e[2]);
            float m6 = fminf(h[6], e[1]), m7 = fminf(h[7], e[0]);
            CE(m0, m4) CE(m1, m5) CE(m2, m6) CE(m3, m7)
            CE(m0, m2) CE(m1, m3) CE(m4, m6) CE(m5, m7)
            CE(m0, m1) CE(m2, m3) CE(m4, m5) CE(m6, m7)
            h[0] = m0; h[1] = m1; h[2] = m2; h[3] = m3;
            h[4] = m4; h[5] = m5; h[6] = m6; h[7] = m7;
        }
        float qsum = 0.0f;
#pragma unroll
        for (int k = 0; k < KNN; ++k) qsum += h[k];
#pragma unroll
        for (int off = 32; off >= 1; off >>= 1) qsum += __shfl_xor(qsum, off, 64);
        if (lane == 0)
            atomicAdd(out, qsum * (1.0f / ((float)B_ * N_ * KNN)));
    }
}

extern "C" void kernel_launch(void* const* d_in, const int* in_sizes, int n_in,
                              void* d_out, int out_size, void* d_ws, size_t ws_size,
                              hipStream_t stream) {
    const float* pts = (const float*)d_in[0];
    float* out = (float*)d_out;
    float4* p4 = (float4*)d_ws;               // 4*8192*16 = 512 KiB scratch

    hipMemsetAsync(out, 0, (size_t)out_size * sizeof(float), stream);
    prepack_kernel<<<(B_ * N_ + 255) / 256, 256, 0, stream>>>(pts, p4);
    knn_tv_kernel<<<B_ * (N_ / 64), BLOCK, 0, stream>>>(p4, out);
}

// Round 6
// 131.984 us; speedup vs baseline: 2.2342x; 1.0396x over previous
//
#include <hip/hip_runtime.h>

// TotalVariationLoss: mean over (B,N,K) of squared distances to the K=8
// nearest neighbors (self excluded) of B*N 3D points. Only the SUM of each
// point's 8 smallest non-self d2 is needed.
//
// Round 6: single-knob occupancy experiment vs round-5 (92 us @ occ 30%).
// WAVES 8->16 (CHUNK 512, BLOCK 1024, grid 512 = 2 blocks/CU = 32 waves/CU).
// Branchless per-8 selection unchanged: Batcher sort-8 (19 CE), bitonic
// top-8 merge (8 min), bitonic cleanup (12 CE).

constexpr int B_    = 4;
constexpr int N_    = 8192;
constexpr int KNN   = 8;
constexpr int WAVES = 16;             // chunks per query group = waves/block
constexpr int BLOCK = WAVES * 64;     // 1024 threads
constexpr int CHUNK = N_ / WAVES;     // 512 candidates per wave
constexpr int NG    = CHUNK / 8;      // 64 groups of 8

#define CE(a, b) { const float _lo = fminf(a, b); b = fmaxf(a, b); a = _lo; }

__global__ __launch_bounds__(256)
void prepack_kernel(const float* __restrict__ pts, float4* __restrict__ p4) {
    const int i = blockIdx.x * 256 + threadIdx.x;
    if (i < B_ * N_) {
        const float x = pts[i * 3 + 0], y = pts[i * 3 + 1], z = pts[i * 3 + 2];
        p4[i] = make_float4(x, y, z, fmaf(x, x, fmaf(y, y, z * z)));
    }
}

__global__ __launch_bounds__(BLOCK, 8)
void knn_tv_kernel(const float4* __restrict__ p4, float* __restrict__ out) {
    __shared__ float lists[(WAVES - 1) * 64][KNN + 1];   // 34.6 KiB, 2-way max

    const int tid   = threadIdx.x;
    const int lane  = tid & 63;
    const int w     = tid >> 6;               // wave id == chunk id
    const int g     = blockIdx.x;
    const int b     = g >> 7;                 // 128 query-groups per batch
    const int qbase = (g & 127) << 6;

    // force wave-uniform candidate base -> s_load scalar broadcast
    const int chunk_off = __builtin_amdgcn_readfirstlane(b * N_ + w * CHUNK);
    const float4* __restrict__ cnd = p4 + chunk_off;

    const float4 q  = p4[b * N_ + qbase + lane];         // coalesced 16B/lane
    const float qsq = q.w;
    const float m2x = -2.0f * q.x, m2y = -2.0f * q.y, m2z = -2.0f * q.z;

    float h[KNN];                              // ascending, h[7] = worst
#pragma unroll
    for (int k = 0; k < KNN; ++k) h[k] = 1e30f;

    // groups [gs0, gs1) contain this wave's own queries as candidates
    // (qbase, w*CHUNK multiples of 64 -> qsel 64-aligned -> 8 full groups)
    const int qsel = qbase - w * CHUNK;
    const bool own = (qsel >= 0) && (qsel < CHUNK);
    const int gs0  = own ? (qsel >> 3) : NG;
    const int gs1  = own ? gs0 + 8 : NG;

    auto do_group = [&](int gg, bool fix) {
        const float4* gp = cnd + gg * 8;
        float d[8];
#pragma unroll
        for (int j = 0; j < 8; ++j) {
            const float4 s = gp[j];            // uniform -> scalar load
            float dd = fmaf(m2x, s.x, fmaf(m2y, s.y, fmaf(m2z, s.z, qsq + s.w)));
            if (fix) dd = (lane == gg * 8 + j - qsel) ? 1e30f : dd;  // self
            d[j] = dd;
        }
        // Batcher odd-even sort-8, ascending (19 CE, depth 6)
        CE(d[0], d[1]) CE(d[2], d[3]) CE(d[4], d[5]) CE(d[6], d[7])
        CE(d[0], d[2]) CE(d[1], d[3]) CE(d[4], d[6]) CE(d[5], d[7])
        CE(d[1], d[2]) CE(d[5], d[6])
        CE(d[0], d[4]) CE(d[1], d[5]) CE(d[2], d[6]) CE(d[3], d[7])
        CE(d[2], d[4]) CE(d[3], d[5])
        CE(d[1], d[2]) CE(d[3], d[4]) CE(d[5], d[6])
        // top-8 of h ∪ d (h asc, d asc): elementwise min vs reversed d -> bitonic
        float m0 = fminf(h[0], d[7]), m1 = fminf(h[1], d[6]);
        float m2 = fminf(h[2], d[5]), m3 = fminf(h[3], d[4]);
        float m4 = fminf(h[4], d[3]), m5 = fminf(h[5], d[2]);
        float m6 = fminf(h[6], d[1]), m7 = fminf(h[7], d[0]);
        // bitonic cleanup -> ascending (12 CE)
        CE(m0, m4) CE(m1, m5) CE(m2, m6) CE(m3, m7)
        CE(m0, m2) CE(m1, m3) CE(m4, m6) CE(m5, m7)
        CE(m0, m1) CE(m2, m3) CE(m4, m5) CE(m6, m7)
        h[0] = m0; h[1] = m1; h[2] = m2; h[3] = m3;
        h[4] = m4; h[5] = m5; h[6] = m6; h[7] = m7;
    };

#pragma unroll 2
    for (int gg = 0; gg < gs0; ++gg) do_group(gg, false);
    for (int gg = gs0; gg < gs1; ++gg) do_group(gg, true);
#pragma unroll 2
    for (int gg = gs1; gg < NG; ++gg) do_group(gg, false);

    // merge the 16 per-wave sorted lists (per query = per lane)
    if (w > 0) {
#pragma unroll
        for (int k = 0; k < KNN; ++k) lists[(w - 1) * 64 + lane][k] = h[k];
    }
    __syncthreads();
    if (w == 0) {
        for (int ww = 0; ww < WAVES - 1; ++ww) {
            float e[KNN];
#pragma unroll
            for (int k = 0; k < KNN; ++k) e[k] = lists[ww * 64 + lane][k];
            float m0 = fminf(h[0], e[7]), m1 = fminf(h[1], e[6]);
            float m2 = fminf(h[2], e[5]), m3 = fminf(h[3], e[4]);
            float m4 = fminf(h[4], e[3]), m5 = fminf(h[5], e[2]);
            float m6 = fminf(h[6], e[1]), m7 = fminf(h[7], e[0]);
            CE(m0, m4) CE(m1, m5) CE(m2, m6) CE(m3, m7)
            CE(m0, m2) CE(m1, m3) CE(m4, m6) CE(m5, m7)
            CE(m0, m1) CE(m2, m3) CE(m4, m5) CE(m6, m7)
            h[0] = m0; h[1] = m1; h[2] = m2; h[3] = m3;
            h[4] = m4; h[5] = m5; h[6] = m6; h[7] = m7;
        }
        float qsum = 0.0f;
#pragma unroll
        for (int k = 0; k < KNN; ++k) qsum += h[k];
#pragma unroll
        for (int off = 32; off >= 1; off >>= 1) qsum += __shfl_xor(qsum, off, 64);
        if (lane == 0)
            atomicAdd(out, qsum * (1.0f / ((float)B_ * N_ * KNN)));
    }
}

extern "C" void kernel_launch(void* const* d_in, const int* in_sizes, int n_in,
                              void* d_out, int out_size, void* d_ws, size_t ws_size,
                              hipStream_t stream) {
    const float* pts = (const float*)d_in[0];
    float* out = (float*)d_out;
    float4* p4 = (float4*)d_ws;               // 4*8192*16 = 512 KiB scratch

    hipMemsetAsync(out, 0, (size_t)out_size * sizeof(float), stream);
    prepack_kernel<<<(B_ * N_ + 255) / 256, 256, 0, stream>>>(pts, p4);
    knn_tv_kernel<<<B_ * (N_ / 64), BLOCK, 0, stream>>>(p4, out);
}